// Round 3
// baseline (3093.634 us; speedup 1.0000x reference)
//
#include <hip/hip_runtime.h>
#include <hip/hip_fp16.h>
#include <hip/hip_cooperative_groups.h>
#include <math.h>

namespace cg = cooperative_groups;

using half8 = __attribute__((ext_vector_type(8))) _Float16;
using f32x4 = __attribute__((ext_vector_type(4))) float;

#define E_DIM 512
#define H_DIM 512
#define V_DIM 32000
#define B_DIM 64
#define T_DIM 32

// ---------------------------------------------------------------------------
// Gather kernel: x0[m=b*T+t][:] = (t==0) ? features[b] : emb[sentence[b][t-1]]
// ---------------------------------------------------------------------------
__global__ __launch_bounds__(128) void build_x(const int* __restrict__ sent,
                                               const float* __restrict__ feat,
                                               const float* __restrict__ emb,
                                               float* __restrict__ x0) {
    int m = blockIdx.x;            // b*T + t
    int b = m >> 5, t = m & 31;
    const float* src = (t == 0) ? (feat + b * E_DIM)
                                : (emb + (long long)sent[b * T_DIM + t - 1] * E_DIM);
    float4 v = ((const float4*)src)[threadIdx.x];
    ((float4*)(x0 + (size_t)m * E_DIM))[threadIdx.x] = v;
}

// ---------------------------------------------------------------------------
// fp32 128x128 tiled GEMM (round-1 verified), computes A @ Bw^T + b1 + b2.
// Used only for xp0 = x0 @ W_ih0^T + b_ih0 + b_hh0.
// ---------------------------------------------------------------------------
__global__ __launch_bounds__(256) void gemm128xp(const float* __restrict__ A,
                                                 const float* __restrict__ Bw,
                                                 const float* __restrict__ bias1,
                                                 const float* __restrict__ bias2,
                                                 float* __restrict__ C) {
    __shared__ float As[16][129];
    __shared__ float Bs[16][129];
    const int tid = threadIdx.x;
    const int tx = tid & 15, ty = tid >> 4;
    const int mtile = blockIdx.x * 128, ntile = blockIdx.y * 128;
    const int mi = ty, ni = tx;
    float acc[8][8] = {};
    const int lcol = tid & 15;
    const int lrow = tid >> 4;

    for (int kc = 0; kc < 512; kc += 16) {
#pragma unroll
        for (int rr = 0; rr < 8; ++rr) {
            int row = lrow + 16 * rr;
            As[lcol][row] = A[(size_t)(mtile + row) * 512 + kc + lcol];
            Bs[lcol][row] = Bw[(size_t)(ntile + row) * 512 + kc + lcol];
        }
        __syncthreads();
#pragma unroll
        for (int k = 0; k < 16; ++k) {
            float a[8], bfr[8];
#pragma unroll
            for (int i = 0; i < 8; ++i) a[i] = As[k][mi + 16 * i];
#pragma unroll
            for (int j = 0; j < 8; ++j) bfr[j] = Bs[k][ni + 16 * j];
#pragma unroll
            for (int i = 0; i < 8; ++i)
#pragma unroll
                for (int j = 0; j < 8; ++j) acc[i][j] += a[i] * bfr[j];
        }
        __syncthreads();
    }
#pragma unroll
    for (int i = 0; i < 8; ++i) {
        int m = mtile + mi + 16 * i;
#pragma unroll
        for (int j = 0; j < 8; ++j) {
            int n = ntile + ni + 16 * j;
            C[(size_t)m * 2048 + n] = acc[i][j] + bias1[n] + bias2[n];
        }
    }
}

// ---------------------------------------------------------------------------
// fp32 -> fp16 conversion (n must be multiple of 1024; used for W_ih1, 1M elems)
// ---------------------------------------------------------------------------
__global__ __launch_bounds__(256) void f32_to_f16_vec(const float* __restrict__ s,
                                                      __half* __restrict__ d) {
    int i = (blockIdx.x * 256 + threadIdx.x) * 4;
    float4 v = *(const float4*)&s[i];
    d[i + 0] = __float2half(v.x);
    d[i + 1] = __float2half(v.y);
    d[i + 2] = __float2half(v.z);
    d[i + 3] = __float2half(v.w);
}

// ---------------------------------------------------------------------------
// Persistent cooperative LSTM: both layers, all 32 steps, one kernel.
//   WG 0..127   (A): layer0. b-tile 16 (wg>>5), j-tile 16 (wg&31).
//                    Whh0 slice (64 rows x 512, stride 516) LDS-resident.
//   WG 128..255 (B): layer1. b-tile 32, j-tile 8.
//                    phase1: xp1[:,t-1,:] slice via fp16 MFMA (hs0h @ Wih1h^T)
//                    phase2: gates = xp1[:,t-2,:] + h1 @ Whh1^T -> cell update
// Pipeline: iter it: A does t=it, B phase1 t=it-1, B phase2 t=it-2. 34 iters.
// h double-buffered in global (parity it&1 read / (it+1)&1 write); c in regs.
// ---------------------------------------------------------------------------
__global__ __launch_bounds__(256) void lstm_persistent(
    const float* __restrict__ xp0,     // [64*32][2048]
    const float* __restrict__ Whh0,    // [2048][512]
    const float* __restrict__ Whh1,    // [2048][512]
    const __half* __restrict__ Wih1h,  // [2048][512] fp16
    const float* __restrict__ bih1,
    const float* __restrict__ bhh1,
    float* __restrict__ h0buf,         // [2][64][512]
    float* __restrict__ h1buf,         // [2][64][512]
    __half* __restrict__ hs0h,         // [32][64][512]  (t-major, feeds phase1 MFMA)
    __half* __restrict__ hs1h)         // [64][32][512]  (m-major, feeds FC)
{
    extern __shared__ float lds[];
    cg::grid_group grid = cg::this_grid();
    const int wg = blockIdx.x;
    const int tid = threadIdx.x;

    if (wg < 128) {
        // ================= A: layer 0 =================
        float(*W)[516] = reinterpret_cast<float(*)[516]>(lds);  // [64][516]
        const int b0 = (wg >> 5) * 16;
        const int j0 = (wg & 31) * 16;
        const int bb = tid >> 4, jj = tid & 15;
        for (int idx = tid; idx < 64 * 128; idx += 256) {
            int row = idx >> 7, k4 = idx & 127;
            int grow = (row >> 4) * 512 + j0 + (row & 15);
            *(float4*)&W[row][k4 * 4] = *(const float4*)&Whh0[(size_t)grow * 512 + k4 * 4];
        }
        __syncthreads();
        const int b = b0 + bb, j = j0 + jj;
        float creg = 0.f;
        for (int it = 0; it < 34; ++it) {
            if (it < 32) {
                const float* hrow = h0buf + ((it & 1) << 15) + (size_t)b * 512;
                float a0 = 0.f, a1 = 0.f, a2 = 0.f, a3 = 0.f;
#pragma unroll 4
                for (int k4 = 0; k4 < 128; ++k4) {
                    float4 hv = ((const float4*)hrow)[k4];
                    float4 w0 = *(const float4*)&W[jj][k4 * 4];
                    float4 w1 = *(const float4*)&W[16 + jj][k4 * 4];
                    float4 w2 = *(const float4*)&W[32 + jj][k4 * 4];
                    float4 w3 = *(const float4*)&W[48 + jj][k4 * 4];
                    a0 += hv.x * w0.x + hv.y * w0.y + hv.z * w0.z + hv.w * w0.w;
                    a1 += hv.x * w1.x + hv.y * w1.y + hv.z * w1.z + hv.w * w1.w;
                    a2 += hv.x * w2.x + hv.y * w2.y + hv.z * w2.z + hv.w * w2.w;
                    a3 += hv.x * w3.x + hv.y * w3.y + hv.z * w3.z + hv.w * w3.w;
                }
                const float* xr = xp0 + ((size_t)b * 32 + it) * 2048 + j;
                float gi = a0 + xr[0];
                float gf = a1 + xr[512];
                float gg = a2 + xr[1024];
                float go = a3 + xr[1536];
                float si = 1.f / (1.f + __expf(-gi));
                float sf = 1.f / (1.f + __expf(-gf));
                float tg = tanhf(gg);
                float so = 1.f / (1.f + __expf(-go));
                creg = sf * creg + si * tg;
                float hv_ = so * tanhf(creg);
                h0buf[(((it + 1) & 1) << 15) + b * 512 + j] = hv_;
                hs0h[((size_t)it * 64 + b) * 512 + j] = __float2half(hv_);
            }
            if (it < 33) { __threadfence(); grid.sync(); }
        }
    } else {
        // ================= B: layer 1 =================
        float(*W)[516] = reinterpret_cast<float(*)[516]>(lds);  // [32][516]
        float* xps = lds + 32 * 516;                            // [2][32][33]
        const int idx = wg - 128;
        const int b0 = (idx >> 6) * 32;
        const int j0 = (idx & 63) * 8;
        const int bb = tid >> 3, jj = tid & 7;
        for (int i2 = tid; i2 < 32 * 128; i2 += 256) {
            int row = i2 >> 7, k4 = i2 & 127;
            int grow = (row >> 3) * 512 + j0 + (row & 7);
            *(float4*)&W[row][k4 * 4] = *(const float4*)&Whh1[(size_t)grow * 512 + k4 * 4];
        }
        float bias[4];
#pragma unroll
        for (int q = 0; q < 4; ++q) {
            int n = q * 512 + j0 + jj;
            bias[q] = bih1[n] + bhh1[n];
        }
        const int lane = tid & 63, wv = tid >> 6;
        const int mh = wv >> 1, nh = wv & 1;
        const int l15 = lane & 15, lk = (lane >> 4) * 8;
        const int arow = b0 + mh * 16 + l15;            // hs0 batch row (A-operand)
        const int nidx = nh * 16 + l15;                 // 0..31 within WG's gate cols
        const int growB = (nidx >> 3) * 512 + j0 + (nidx & 7);  // Wih1 row (B-operand)
        const int b = b0 + bb, j = j0 + jj;
        float creg = 0.f;
        __syncthreads();
        for (int it = 0; it < 34; ++it) {
            // ---- phase1: xp1 slice for t1 = it-1 via fp16 MFMA ----
            if (it >= 1 && it < 33) {
                const int t1 = it - 1;
                const __half* hsrc = hs0h + (size_t)t1 * 32768;
                f32x4 acc = {0.f, 0.f, 0.f, 0.f};
#pragma unroll
                for (int kc = 0; kc < 512; kc += 32) {
                    half8 av = *(const half8*)&hsrc[(size_t)arow * 512 + kc + lk];
                    half8 bv = *(const half8*)&Wih1h[(size_t)growB * 512 + kc + lk];
                    acc = __builtin_amdgcn_mfma_f32_16x16x32_f16(av, bv, acc, 0, 0, 0);
                }
                float* xb = xps + (it & 1) * (32 * 33);
#pragma unroll
                for (int r = 0; r < 4; ++r)
                    xb[(mh * 16 + (lane >> 4) * 4 + r) * 33 + nidx] = acc[r];
            }
            // ---- phase2: layer1 step t2 = it-2 ----
            if (it >= 2) {
                const int t2 = it - 2;
                const float* hrow = h1buf + ((it & 1) << 15) + (size_t)b * 512;
                float a0 = 0.f, a1 = 0.f, a2 = 0.f, a3 = 0.f;
#pragma unroll 4
                for (int k4 = 0; k4 < 128; ++k4) {
                    float4 hv = ((const float4*)hrow)[k4];
                    float4 w0 = *(const float4*)&W[jj][k4 * 4];
                    float4 w1 = *(const float4*)&W[8 + jj][k4 * 4];
                    float4 w2 = *(const float4*)&W[16 + jj][k4 * 4];
                    float4 w3 = *(const float4*)&W[24 + jj][k4 * 4];
                    a0 += hv.x * w0.x + hv.y * w0.y + hv.z * w0.z + hv.w * w0.w;
                    a1 += hv.x * w1.x + hv.y * w1.y + hv.z * w1.z + hv.w * w1.w;
                    a2 += hv.x * w2.x + hv.y * w2.y + hv.z * w2.z + hv.w * w2.w;
                    a3 += hv.x * w3.x + hv.y * w3.y + hv.z * w3.z + hv.w * w3.w;
                }
                const float* xb = xps + ((it - 1) & 1) * (32 * 33) + bb * 33;
                float gi = a0 + xb[jj] + bias[0];
                float gf = a1 + xb[8 + jj] + bias[1];
                float gg = a2 + xb[16 + jj] + bias[2];
                float go = a3 + xb[24 + jj] + bias[3];
                float si = 1.f / (1.f + __expf(-gi));
                float sf = 1.f / (1.f + __expf(-gf));
                float tg = tanhf(gg);
                float so = 1.f / (1.f + __expf(-go));
                creg = sf * creg + si * tg;
                float hv_ = so * tanhf(creg);
                h1buf[(((it + 1) & 1) << 15) + b * 512 + j] = hv_;
                hs1h[((size_t)b * 32 + t2) * 512 + j] = __float2half(hv_);
            }
            if (it < 33) { __threadfence(); grid.sync(); }
        }
    }
}

// ---------------------------------------------------------------------------
// FC: out[b][v][t] = hs1[b,t,:] . fc_W[v,:] + fc_b[v], fp16 MFMA.
// A = hs1h fp16 [2048][512]; Bw = fc_W fp32 (converted in-register).
// Block 256 = 4 waves (2x2), wave tile 64x64, block tile 128x128.
// Grid (16 m-tiles fast, 250 n-tiles) so co-dispatched blocks share fc_W stripe.
// ---------------------------------------------------------------------------
__global__ __launch_bounds__(256) void fc_mfma(const __half* __restrict__ A,
                                               const float* __restrict__ Bw,
                                               const float* __restrict__ bias,
                                               float* __restrict__ out) {
    const int tid = threadIdx.x;
    const int lane = tid & 63, wv = tid >> 6;
    const int wm = wv >> 1, wn = wv & 1;
    const int m_base = blockIdx.x * 128 + wm * 64;
    const int n_base = blockIdx.y * 128 + wn * 64;
    const int l15 = lane & 15, lk = (lane >> 4) * 8;
    f32x4 zero = {0.f, 0.f, 0.f, 0.f};
    f32x4 acc[4][4];
#pragma unroll
    for (int i = 0; i < 4; ++i)
#pragma unroll
        for (int j2 = 0; j2 < 4; ++j2) acc[i][j2] = zero;

    for (int kc = 0; kc < 512; kc += 32) {
        half8 a[4], bfr[4];
#pragma unroll
        for (int i = 0; i < 4; ++i)
            a[i] = *(const half8*)&A[(size_t)(m_base + i * 16 + l15) * 512 + kc + lk];
#pragma unroll
        for (int j2 = 0; j2 < 4; ++j2) {
            const float* bp = &Bw[(size_t)(n_base + j2 * 16 + l15) * 512 + kc + lk];
            float4 x0 = *(const float4*)bp;
            float4 x1 = *(const float4*)(bp + 4);
            half8 hb;
            hb[0] = (_Float16)x0.x; hb[1] = (_Float16)x0.y;
            hb[2] = (_Float16)x0.z; hb[3] = (_Float16)x0.w;
            hb[4] = (_Float16)x1.x; hb[5] = (_Float16)x1.y;
            hb[6] = (_Float16)x1.z; hb[7] = (_Float16)x1.w;
            bfr[j2] = hb;
        }
#pragma unroll
        for (int i = 0; i < 4; ++i)
#pragma unroll
            for (int j2 = 0; j2 < 4; ++j2)
                acc[i][j2] = __builtin_amdgcn_mfma_f32_16x16x32_f16(a[i], bfr[j2], acc[i][j2], 0, 0, 0);
    }
#pragma unroll
    for (int i = 0; i < 4; ++i) {
        const int m0 = m_base + i * 16 + (lane >> 4) * 4;  // 4 consecutive t, same b
        const int bq = m0 >> 5;
        const int t0 = m0 & 31;
#pragma unroll
        for (int j2 = 0; j2 < 4; ++j2) {
            const int v = n_base + j2 * 16 + l15;
            const float bv = bias[v];
            float4 o;
            o.x = acc[i][j2][0] + bv;
            o.y = acc[i][j2][1] + bv;
            o.z = acc[i][j2][2] + bv;
            o.w = acc[i][j2][3] + bv;
            *(float4*)&out[((size_t)bq * V_DIM + v) * 32 + t0] = o;
        }
    }
}

// ---------------------------------------------------------------------------
extern "C" void kernel_launch(void* const* d_in, const int* in_sizes, int n_in,
                              void* d_out, int out_size, void* d_ws, size_t ws_size,
                              hipStream_t stream) {
    const int*   sent  = (const int*)d_in[0];
    const float* feat  = (const float*)d_in[1];
    const float* emb   = (const float*)d_in[3];
    const float* W_ih0 = (const float*)d_in[4];
    const float* W_hh0 = (const float*)d_in[5];
    const float* b_ih0 = (const float*)d_in[6];
    const float* b_hh0 = (const float*)d_in[7];
    const float* W_ih1 = (const float*)d_in[8];
    const float* W_hh1 = (const float*)d_in[9];
    const float* b_ih1 = (const float*)d_in[10];
    const float* b_hh1 = (const float*)d_in[11];
    const float* fc_W  = (const float*)d_in[12];
    const float* fc_b  = (const float*)d_in[13];
    float* out = (float*)d_out;
    float* ws  = (float*)d_ws;

    // workspace layout (float offsets)
    float*  x0    = ws;                                  // 1,048,576
    float*  xp0   = ws + 1048576;                        // 4,194,304
    float*  h0buf = ws + 5242880;                        // 65,536 (2x64x512)
    float*  h1buf = ws + 5308416;                        // 65,536
    __half* hs0h  = (__half*)(ws + 5373952);             // 1,048,576 halves
    __half* hs1h  = (__half*)(ws + 5898240);             // 1,048,576 halves
    __half* Wih1h = (__half*)(ws + 6422528);             // 1,048,576 halves
    // end: 6,946,816 floats = 27.8 MB

    build_x<<<dim3(2048), dim3(128), 0, stream>>>(sent, feat, emb, x0);
    gemm128xp<<<dim3(16, 16), dim3(256), 0, stream>>>(x0, W_ih0, b_ih0, b_hh0, xp0);
    f32_to_f16_vec<<<dim3(1024), dim3(256), 0, stream>>>(W_ih1, Wih1h);
    hipMemsetAsync(h0buf, 0, 2 * 65536 * sizeof(float), stream);  // h0buf + h1buf

    {
        const float* a0 = xp0;  const float* a1 = W_hh0; const float* a2 = W_hh1;
        const __half* a3 = Wih1h;
        const float* a4 = b_ih1; const float* a5 = b_hh1;
        float* a6 = h0buf; float* a7 = h1buf;
        __half* a8 = hs0h; __half* a9 = hs1h;
        void* args[] = {(void*)&a0, (void*)&a1, (void*)&a2, (void*)&a3, (void*)&a4,
                        (void*)&a5, (void*)&a6, (void*)&a7, (void*)&a8, (void*)&a9};
        hipFuncSetAttribute(reinterpret_cast<const void*>(lstm_persistent),
                            hipFuncAttributeMaxDynamicSharedMemorySize, 64 * 516 * 4);
        hipLaunchCooperativeKernel(lstm_persistent, dim3(256), dim3(256), args,
                                   (unsigned)(64 * 516 * 4), stream);
    }

    fc_mfma<<<dim3(16, 250), dim3(256), 0, stream>>>(hs1h, fc_W, fc_b, out);
}